// Round 9
// baseline (410.623 us; speedup 1.0000x reference)
//
#include <hip/hip_runtime.h>
#include <math.h>

#define BATCH 4
#define SEQ 2048
#define DMODEL 256
#define NH 4
#define HD 64
#define MROWS 8192
#define QKSCALE 0.4246608905f  // sqrt(0.125 * log2(e)): qk pre-scaled => exp2 direct

typedef short bf16x8 __attribute__((ext_vector_type(8)));
typedef float f32x4 __attribute__((ext_vector_type(4)));
typedef unsigned short us;

#if __has_builtin(__builtin_amdgcn_exp2f)
#define EXP2(x) __builtin_amdgcn_exp2f(x)
#else
#define EXP2(x) exp2f(x)
#endif

__device__ __forceinline__ us f2bf(float x) {  // RNE
  union { float f; unsigned int u; } v;
  v.f = x;
  unsigned int r = (v.u + 0x7FFF + ((v.u >> 16) & 1)) >> 16;
  return (us)r;
}
__device__ __forceinline__ float bf2f(us u) {
  union { unsigned int u; float f; } v;
  v.u = ((unsigned int)u) << 16;
  return v.f;
}
__device__ __forceinline__ unsigned int fbits(float x) {
  union { float f; unsigned int u; } v;
  v.f = x;
  return v.u;
}
// v_perm pack: [bf16_trunc(lo) | bf16_trunc(hi)<<16] in one instruction.
__device__ __forceinline__ unsigned int pk2bf(float lo, float hi) {
  return __builtin_amdgcn_perm(fbits(hi), fbits(lo), 0x07060302u);
}
// Async global->LDS DMA, 16B/lane; lane i lands at base + i*16.
__device__ __forceinline__ void dma16(const void* g, void* l) {
  auto gp = (const __attribute__((address_space(1))) unsigned int*)(unsigned long long)(uintptr_t)g;
  auto lp = (__attribute__((address_space(3))) unsigned int*)(unsigned int)(uintptr_t)l;
  __builtin_amdgcn_global_load_lds(gp, lp, 16, 0, 0);
}

// ---------------------------------------------------------------------------
// prep_k: casts + weight transposes + out-proj fold + ZERO tickets/ln-stats.
//   [0,4096) cast x | [4096,5634) weights | [5634,5891) wcomb | [5891,5924) zero
// ---------------------------------------------------------------------------
__global__ __launch_bounds__(256) void prep_k(
    const float* __restrict__ x0, const float* __restrict__ x1,
    const float* __restrict__ Wqk, const float* __restrict__ Wv,
    const float* __restrict__ W0, const float* __restrict__ W3,
    const float* __restrict__ Wout,
    const float* __restrict__ bqk, const float* __restrict__ bv,
    const float* __restrict__ b0, const float* __restrict__ bout,
    us* __restrict__ x0b, us* __restrict__ x1b,
    us* __restrict__ Wqvt, us* __restrict__ W1t, us* __restrict__ W3t,
    float* __restrict__ bias_qv, float* __restrict__ bias1,
    float* __restrict__ zbase) {
  const int bid = blockIdx.x, t = threadIdx.x;
  if (bid < 4096) {
    const int n4 = (MROWS * DMODEL) / 4;
    int i = bid * 256 + t;
    const float* src = (i < n4) ? x0 : x1;
    us* dst = (i < n4) ? x0b : x1b;
    int j = (i < n4) ? i : i - n4;
    float4 v = *(const float4*)&src[j * 4];
    ushort4 o = {f2bf(v.x), f2bf(v.y), f2bf(v.z), f2bf(v.w)};
    *(ushort4*)&dst[j * 4] = o;
  } else if (bid < 5634) {
    int gid = (bid - 4096) * 256 + t;
    if (gid < 65536) {
      int k = gid >> 8, j = gid & 255;
      Wqvt[j * 256 + k] = f2bf(Wqk[gid]);
    } else if (gid < 131072) {
      int i = gid - 65536;
      int k = i >> 8, j = i & 255;
      Wqvt[(256 + j) * 256 + k] = f2bf(Wv[i]);
    } else if (gid < 262144) {
      int i = gid - 131072;
      int k = i >> 9, j = i & 511;
      W1t[j * 512 + k] = f2bf(W0[i]);
    } else if (gid < 393216) {
      int i = gid - 262144;
      int k = i >> 8, j = i & 255;
      W3t[j * 512 + k] = f2bf(W3[i]);
    } else if (gid < 393728) {
      int j = gid - 393216;
      bias_qv[j] = (j < 256) ? bqk[j] : bv[j - 256];
    }
  } else if (bid < 5891) {
    int i = bid - 5634;  // [0,257)
    if (i < 256) {
      float a0 = 0.f, a1 = 0.f;
      for (int k0 = 0; k0 < 256; k0 += 8) {
        float wk[8], r0[8], r1[8];
#pragma unroll
        for (int u = 0; u < 8; ++u) {
          wk[u] = Wout[i * 256 + k0 + u];
          const float* row = &W0[(size_t)(256 + k0 + u) * 512];
          r0[u] = row[t];
          r1[u] = row[t + 256];
        }
#pragma unroll
        for (int u = 0; u < 8; ++u) { a0 += wk[u] * r0[u]; a1 += wk[u] * r1[u]; }
      }
      W1t[t * 512 + 256 + i] = f2bf(a0);
      W1t[(t + 256) * 512 + 256 + i] = f2bf(a1);
    } else {
      float a0 = b0[t], a1 = b0[t + 256];
      for (int k = 0; k < 256; ++k) {
        float bk = bout[k];
        const float* row = &W0[(size_t)(256 + k) * 512];
        a0 += bk * row[t];
        a1 += bk * row[t + 256];
      }
      bias1[t] = a0;
      bias1[t + 256] = a1;
    }
  } else {
    // zero tickets (4 KB) + ln stats (128 KB): 33792 floats total
    int i = (bid - 5891) * 256 + t;
    if (i * 4 < 33792) {
      float4 zz = {0.f, 0.f, 0.f, 0.f};
      *(float4*)&zbase[i * 4] = zz;
    }
  }
}

// ---------------------------------------------------------------------------
// gemm6: MFMA bf16 GEMM, 128x128 tile, dbuf DMA staging, XCD remap,
// coalesced bf16 epilogue via LDS bounce. Grid (64,4,2) = 512 blocks.
//   MODE 0 (QV, N=512): coltile<2 -> qk *QKSCALE; >=2 -> Vt transposed
//   MODE 1 (FFN1, N=512): A = concat(Ax, Am); bf16 out + LN-stats atomics
// ---------------------------------------------------------------------------
template <int MODE>
__global__ __launch_bounds__(256) void gemm6(
    const us* __restrict__ A0, const us* __restrict__ A1,
    const us* __restrict__ Am0, const us* __restrict__ Am1,
    const us* __restrict__ Wt, const float* __restrict__ bias,
    void* __restrict__ C0_, void* __restrict__ C1_,
    void* __restrict__ V0_, void* __restrict__ V1_, int K,
    float* __restrict__ lnsum, float* __restrict__ lnsq) {
  constexpr int BUFS = 16384;  // shorts: A 8192 + B 8192
  __shared__ us lds[2 * BUFS];

  const int t = threadIdx.x, w = t >> 6, lane = t & 63;
  const int qd = lane >> 4, l15 = lane & 15;

  const int flat = blockIdx.x + 64 * (blockIdx.y + 4 * blockIdx.z);
  const int xcd = flat & 7, slot = flat >> 3;
  const int xz = (xcd << 4) + (slot >> 2);
  const int bx = xz & 63, z = xz >> 6, coltile = slot & 3;
  const int row0 = bx * 128, col0 = coltile * 128;

  const us* Ax = z ? A1 : A0;
  const us* Am = z ? Am1 : Am0;
  const int qr = w >> 1, qc = w & 1;

  f32x4 acc[4][4];
#pragma unroll
  for (int i = 0; i < 4; ++i)
#pragma unroll
    for (int j = 0; j < 4; ++j) acc[i][j] = (f32x4){0.f, 0.f, 0.f, 0.f};

  const int NK = K >> 6;
#pragma unroll
  for (int pp = 0; pp < 8; ++pp) {
    int g = pp * 4 + w;
    const us* src;
    if (g < 16) {
      int tm = g >> 1, s = g & 1;
      src = &Ax[(size_t)(row0 + tm * 16 + l15) * ((MODE == 1) ? 256 : K) + s * 32 + qd * 8];
    } else {
      int gb = g - 16, tn = gb >> 1, s = gb & 1;
      src = &Wt[(size_t)(col0 + tn * 16 + l15) * K + s * 32 + qd * 8];
    }
    dma16(src, &lds[g * 512]);
  }
  __syncthreads();

  int bsel = 0;
  for (int it = 0; it < NK; ++it) {
    if (it + 1 < NK) {
      int k0 = (it + 1) << 6;
#pragma unroll
      for (int pp = 0; pp < 8; ++pp) {
        int g = pp * 4 + w;
        const us* src;
        if (g < 16) {
          int tm = g >> 1, s = g & 1;
          const us* Ap = Ax;
          int kk = k0 + s * 32 + qd * 8, lda = K;
          if (MODE == 1) {
            Ap = (k0 < 256) ? Ax : Am;
            kk &= 255;
            lda = 256;
          }
          src = &Ap[(size_t)(row0 + tm * 16 + l15) * lda + kk];
        } else {
          int gb = g - 16, tn = gb >> 1, s = gb & 1;
          src = &Wt[(size_t)(col0 + tn * 16 + l15) * K + k0 + s * 32 + qd * 8];
        }
        dma16(src, &lds[(bsel ^ 1) * BUFS + g * 512]);
      }
    }
    const us* L = &lds[bsel * BUFS];
#pragma unroll
    for (int s = 0; s < 2; ++s) {
      bf16x8 af[4], bfr[4];
#pragma unroll
      for (int i = 0; i < 4; ++i) {
        af[i] = *(const bf16x8*)&L[(((qr * 4 + i) * 2 + s) * 64 + lane) * 8];
        bfr[i] = *(const bf16x8*)&L[8192 + (((qc * 4 + i) * 2 + s) * 64 + lane) * 8];
      }
#pragma unroll
      for (int i = 0; i < 4; ++i)
#pragma unroll
        for (int j = 0; j < 4; ++j)
          acc[i][j] = __builtin_amdgcn_mfma_f32_16x16x32_bf16(af[i], bfr[j], acc[i][j], 0, 0, 0);
    }
    __syncthreads();
    bsel ^= 1;
  }

  if (MODE == 0 && coltile >= 2) {
    // Vt transposed via LDS bounce (stride 130).
    int base = qc * 8320;
#pragma unroll
    for (int j = 0; j < 4; ++j) {
      int col = col0 + qc * 64 + j * 16 + l15;
      float bb = bias[col];
#pragma unroll
      for (int i = 0; i < 4; ++i)
#pragma unroll
        for (int r = 0; r < 4; ++r)
          lds[base + (j * 16 + l15) * 130 + (qr * 64 + i * 16 + qd * 4 + r)] =
              f2bf(acc[i][j][r] + bb);
    }
    __syncthreads();
    us* Vt = (us*)(z ? V1_ : V0_);
    int b_ = row0 >> 11, seq0 = row0 & 2047;
    for (int c = t; c < 2048; c += 256) {
      int hh = c >> 10, cc = c & 1023;
      int dloc = cc >> 4, scc = cc & 15;
      int h = (coltile - 2) * 2 + hh;
      uint4 d = *(const uint4*)&lds[hh * 8320 + dloc * 130 + scc * 8];
      *(uint4*)&Vt[((size_t)(b_ * NH + h) * HD + dloc) * SEQ + seq0 + scc * 8] = d;
    }
    return;
  }

  // bf16 natural out via LDS bounce (stride 132) -> coalesced uint4 stores.
#pragma unroll
  for (int j = 0; j < 4; ++j) {
    int cl = qc * 64 + j * 16 + l15;
    float bb = bias[col0 + cl];
#pragma unroll
    for (int i = 0; i < 4; ++i)
#pragma unroll
      for (int r = 0; r < 4; ++r) {
        float v = acc[i][j][r] + bb;
        if (MODE == 0) v *= QKSCALE;
        lds[(qr * 64 + i * 16 + qd * 4 + r) * 132 + cl] = f2bf(v);
      }
  }
  __syncthreads();
  us* C = (us*)(z ? C1_ : C0_);
  const int ldc = (MODE == 0) ? 256 : 512;
  for (int c = t; c < 2048; c += 256) {
    int rl = c >> 4, c8 = (c & 15) * 8;
    uint4 d = *(const uint4*)&lds[rl * 132 + c8];
    *(uint4*)&C[(size_t)(row0 + rl) * ldc + col0 + c8] = d;
  }

  if (MODE == 1) {
    // LN stats: per-row sum/sumsq of this 128-col slice -> atomics.
    int rl = t >> 1, hf = t & 1;
    float s1 = 0.f, s2 = 0.f;
#pragma unroll
    for (int c = 0; c < 64; c += 8) {
      uint4 d = *(const uint4*)&lds[rl * 132 + hf * 64 + c];
      unsigned int uu[4] = {d.x, d.y, d.z, d.w};
#pragma unroll
      for (int i = 0; i < 4; ++i) {
        float a = bf2f((us)(uu[i] & 0xFFFF));
        float b = bf2f((us)(uu[i] >> 16));
        s1 += a + b;
        s2 += a * a + b * b;
      }
    }
    s1 += __shfl_xor(s1, 1);
    s2 += __shfl_xor(s2, 1);
    if (hf == 0) {
      atomicAdd(&lnsum[z * MROWS + row0 + rl], s1);
      atomicAdd(&lnsq[z * MROWS + row0 + rl], s2);
    }
  }
}

// ---------------------------------------------------------------------------
// flash_v8: register-P MFMA flash, kv-split x2, both dirs, dbuf DMA prefetch,
// XCD remap, and IN-KERNEL TAIL COMBINE (ticket atomics + threadfence):
// second finisher of each (dir,b,h,qt) pair merges partner partials with its
// register accumulator and writes m bf16 directly. combine_k is gone.
// ---------------------------------------------------------------------------
__global__ __launch_bounds__(256) void flash_v8(
    const us* __restrict__ qk0, const us* __restrict__ qk1,
    const us* __restrict__ vt0, const us* __restrict__ vt1,
    float* __restrict__ Opart, float* __restrict__ lpart,
    us* __restrict__ m0b, us* __restrict__ m1b, int* __restrict__ tickets) {
  __shared__ us lds[16384];  // 2 x 16KB buffers
  __shared__ int sOld;
  const int t = threadIdx.x, w = t >> 6, lane = t & 63;
  const int qd = lane >> 4, l15 = lane & 15;

  const int flat = blockIdx.x + 32 * (blockIdx.y + 4 * blockIdx.z);
  const int xcd = flat & 7, slot = flat >> 3;
  const int combo = (xcd << 2) + (slot >> 5);
  const int qs = slot & 31;
  const int qt = qs & 15, half = qs >> 4;
  const int dir = combo >> 4, bh = combo & 15, b = bh >> 2, h = bh & 3;

  const us* Qb = dir ? qk1 : qk0;
  const us* Kb = dir ? qk0 : qk1;
  const us* Vt = dir ? vt0 : vt1;
  float* Op = Opart + (size_t)(dir * 2 + half) * (MROWS * DMODEL);
  float* lp = lpart + ((size_t)(dir * 2 + half) * NH + h) * MROWS;
  const size_t qrow0 = (size_t)b * SEQ + (size_t)qt * 128;
  const int hoff = h * HD;
  const us* vtb = Vt + (size_t)(b * NH + h) * HD * SEQ;
  const int kt0 = half * 16;

  const us* sp[4];
  int sstr[4];
#pragma unroll
  for (int pp = 0; pp < 4; ++pp) {
    int g = pp * 4 + w;
    if (g < 8) {
      int tk = g >> 1, s = g & 1;
      int kvl = (tk >> 1) * 32 + (l15 >> 2) * 8 + (tk & 1) * 4 + (l15 & 3);  // pi
      sp[pp] = &Kb[(size_t)(b * SEQ + kt0 * 64 + kvl) * DMODEL + hoff + s * 32 + qd * 8];
      sstr[pp] = 64 * DMODEL;
    } else {
      int td = (g - 8) >> 1, s = g & 1;
      sp[pp] = &vtb[(size_t)(td * 16 + l15) * SEQ + kt0 * 64 + s * 32 + qd * 8];
      sstr[pp] = 64;
    }
  }

  bf16x8 qf[2][2];
#pragma unroll
  for (int qh = 0; qh < 2; ++qh)
#pragma unroll
    for (int s = 0; s < 2; ++s)
      qf[qh][s] = *(const bf16x8*)&Qb[(qrow0 + w * 32 + qh * 16 + l15) * DMODEL + hoff + s * 32 + qd * 8];

  f32x4 Oacc[2][4];
#pragma unroll
  for (int qh = 0; qh < 2; ++qh)
#pragma unroll
    for (int td = 0; td < 4; ++td) Oacc[qh][td] = (f32x4){0.f, 0.f, 0.f, 0.f};
  float l_lane[2] = {0.f, 0.f};

#pragma unroll
  for (int pp = 0; pp < 4; ++pp) {
    dma16(sp[pp], &lds[(pp * 4 + w) * 512]);
    sp[pp] += sstr[pp];
  }
  __syncthreads();

  int bsel = 0;
  for (int it = 0; it < 16; ++it) {
    if (it < 15) {
#pragma unroll
      for (int pp = 0; pp < 4; ++pp) {
        dma16(sp[pp], &lds[(bsel ^ 1) * 8192 + (pp * 4 + w) * 512]);
        sp[pp] += sstr[pp];
      }
    }
    const us* L = &lds[bsel * 8192];

    bf16x8 kf[4][2], vf[4][2];
#pragma unroll
    for (int tk = 0; tk < 4; ++tk)
#pragma unroll
      for (int s = 0; s < 2; ++s) {
        kf[tk][s] = *(const bf16x8*)&L[((tk * 2 + s) * 64 + lane) * 8];
        vf[tk][s] = *(const bf16x8*)&L[((8 + tk * 2 + s) * 64 + lane) * 8];
      }

#pragma unroll
    for (int qh = 0; qh < 2; ++qh) {
      f32x4 S[4];
#pragma unroll
      for (int tk = 0; tk < 4; ++tk) {
        f32x4 a = {0.f, 0.f, 0.f, 0.f};
        a = __builtin_amdgcn_mfma_f32_16x16x32_bf16(kf[tk][0], qf[qh][0], a, 0, 0, 0);
        a = __builtin_amdgcn_mfma_f32_16x16x32_bf16(kf[tk][1], qf[qh][1], a, 0, 0, 0);
        S[tk] = a;
      }
      float p[4][4];
      float rs = 0.f;
#pragma unroll
      for (int tk = 0; tk < 4; ++tk)
#pragma unroll
        for (int r = 0; r < 4; ++r) {
          float pv = EXP2(S[tk][r]);
          p[tk][r] = pv;
          rs += pv;
        }
      l_lane[qh] += rs;
      union { bf16x8 v; unsigned int u[4]; } pk0, pk1;
      pk0.u[0] = pk2bf(p[0][0], p[0][1]);
      pk0.u[1] = pk2bf(p[0][2], p[0][3]);
      pk0.u[2] = pk2bf(p[1][0], p[1][1]);
      pk0.u[3] = pk2bf(p[1][2], p[1][3]);
      pk1.u[0] = pk2bf(p[2][0], p[2][1]);
      pk1.u[1] = pk2bf(p[2][2], p[2][3]);
      pk1.u[2] = pk2bf(p[3][0], p[3][1]);
      pk1.u[3] = pk2bf(p[3][2], p[3][3]);
#pragma unroll
      for (int td = 0; td < 4; ++td) {
        Oacc[qh][td] = __builtin_amdgcn_mfma_f32_16x16x32_bf16(pk0.v, vf[td][0], Oacc[qh][td], 0, 0, 0);
        Oacc[qh][td] = __builtin_amdgcn_mfma_f32_16x16x32_bf16(pk1.v, vf[td][1], Oacc[qh][td], 0, 0, 0);
      }
    }
    __syncthreads();
    bsel ^= 1;
  }

  // Partials: per-row l and fp32 O-numerator (C-layout scatter).
  float lred[2];
#pragma unroll
  for (int qh = 0; qh < 2; ++qh) {
    float l = l_lane[qh];
    l += __shfl_xor(l, 16);
    l += __shfl_xor(l, 32);
    lred[qh] = l;
    if (qd == 0) lp[qrow0 + w * 32 + qh * 16 + l15] = l;
#pragma unroll
    for (int r = 0; r < 4; ++r) {
      size_t row = qrow0 + w * 32 + qh * 16 + qd * 4 + r;
#pragma unroll
      for (int td = 0; td < 4; ++td)
        Op[row * DMODEL + hoff + td * 16 + l15] = Oacc[qh][td][r];
    }
  }

  // Tail combine: second finisher of (dir,b,h,qt) merges and writes m.
  __threadfence();
  __syncthreads();
  if (t == 0) sOld = atomicAdd(&tickets[((dir * BATCH + b) * NH + h) * 16 + qt], 1);
  __syncthreads();
  if (sOld == 1) {
    __threadfence();
    us* m = dir ? m1b : m0b;
    const float* Opp = Opart + (size_t)(dir * 2 + (half ^ 1)) * (MROWS * DMODEL);
    const float* lpp = lpart + ((size_t)(dir * 2 + (half ^ 1)) * NH + h) * MROWS;
#pragma unroll
    for (int qh = 0; qh < 2; ++qh) {
      float inv = 1.0f / (lred[qh] + lpp[qrow0 + w * 32 + qh * 16 + l15]);
#pragma unroll
      for (int r = 0; r < 4; ++r) {
        float lq = __shfl(inv, qd * 20 + r, 64);  // lane with l15 == qd*4+r
        size_t row = qrow0 + w * 32 + qh * 16 + qd * 4 + r;
#pragma unroll
        for (int td = 0; td < 4; ++td) {
          float o = Oacc[qh][td][r] + Opp[row * DMODEL + hoff + td * 16 + l15];
          m[row * DMODEL + hoff + td * 16 + l15] = f2bf(o * lq);
        }
      }
    }
  }
}

// ---------------------------------------------------------------------------
// ffn2_k: out = x + gelu(LN(y)) @ W3 + b3, LN+GELU applied DURING A-staging
// using the stats accumulated by FFN1. Tile 64 rows x 128 cols, 4 waves as
// 2x2 quadrants of 32x64. B via DMA, A manual (load y, LN+gelu, perm-pack,
// ds_write_b128). Grid (128, 2, 2) = 512 blocks.
// ---------------------------------------------------------------------------
__global__ __launch_bounds__(256) void ffn2_k(
    const us* __restrict__ y0b, const us* __restrict__ y1b,
    const us* __restrict__ W3t, const float* __restrict__ b3,
    const float* __restrict__ x0, const float* __restrict__ x1,
    float* __restrict__ out0, float* __restrict__ out1,
    const float* __restrict__ lnsum, const float* __restrict__ lnsq,
    const float* __restrict__ sc, const float* __restrict__ bi) {
  constexpr int BUFS = 12288;  // shorts: A 4096 + B 8192
  __shared__ us lds[2 * BUFS];  // 48 KB
  const int t = threadIdx.x, w = t >> 6, lane = t & 63;
  const int qd = lane >> 4, l15 = lane & 15;

  const int flat = blockIdx.x + 128 * (blockIdx.y + 2 * blockIdx.z);
  const int xcd = flat & 7, slot = flat >> 3;        // slot in [0,64)
  const int xz = xcd * 32 + (slot >> 1);             // [0,256)
  const int bx = xz & 127, z = xz >> 7, ct = slot & 1;
  const int row0 = bx * 64, col0 = ct * 128;

  const us* Y = z ? y1b : y0b;
  const float* lsum = lnsum + z * MROWS;
  const float* lsq = lnsq + z * MROWS;
  const int qr = w >> 1, qc = w & 1;

  f32x4 acc[2][4];
#pragma unroll
  for (int i = 0; i < 2; ++i)
#pragma unroll
    for (int j = 0; j < 4; ++j) acc[i][j] = (f32x4){0.f, 0.f, 0.f, 0.f};

  // Staging helpers
  auto stage = [&](int k0, us* buf) {
    // B: 16 granules via DMA (issued first, flies during A's VALU work)
#pragma unroll
    for (int pp = 0; pp < 4; ++pp) {
      int gb = pp * 4 + w;
      int tn = gb >> 1, s = gb & 1;
      dma16(&W3t[(size_t)(col0 + tn * 16 + l15) * 512 + k0 + s * 32 + qd * 8],
            &buf[4096 + gb * 512]);
    }
    // A: 8 granules manual with LN+GELU
#pragma unroll
    for (int pp = 0; pp < 2; ++pp) {
      int g = pp * 4 + w;
      int tm = g >> 1, s = g & 1;
      int row = row0 + tm * 16 + l15;
      int kk = k0 + s * 32 + qd * 8;
      uint4 d = *(const uint4*)&Y[(size_t)row * 512 + kk];
      float mu = lsum[row] * (1.0f / 512.0f);
      float vr = lsq[row] * (1.0f / 512.0f) - mu * mu;
      float rstd = rsqrtf(vr + 1e-5f);
      unsigned int uu[4] = {d.x, d.y, d.z, d.w};
      unsigned int ou[4];
#pragma unroll
      for (int i = 0; i < 4; ++i) {
        int k_ = kk + 2 * i;
        float a = bf2f((us)(uu[i] & 0xFFFF));
        float bq = bf2f((us)(uu[i] >> 16));
        float g0 = (a - mu) * rstd * sc[k_] + bi[k_];
        float g1 = (bq - mu) * rstd * sc[k_ + 1] + bi[k_ + 1];
        g0 = 0.5f * g0 * (1.0f + erff(g0 * 0.70710678118654752f));
        g1 = 0.5f * g1 * (1.0f + erff(g1 * 0.70710678118654752f));
        ou[i] = pk2bf(g0, g1);
      }
      uint4 o = {ou[0], ou[1], ou[2], ou[3]};
      *(uint4*)&buf[g * 512 + lane * 8] = o;
    }
  };

  stage(0, lds);
  __syncthreads();
  int bsel = 0;
  for (int it = 0; it < 8; ++it) {
    if (it < 7) stage((it + 1) * 64, &lds[(bsel ^ 1) * BUFS]);
    const us* L = &lds[bsel * BUFS];
#pragma unroll
    for (int s = 0; s < 2; ++s) {
      bf16x8 af[2], bfr[4];
#pragma unroll
      for (int i = 0; i < 2; ++i)
        af[i] = *(const bf16x8*)&L[(((qr * 2 + i) * 2 + s) * 64 + lane) * 8];
#pragma unroll
      for (int j = 0; j < 4; ++j)
        bfr[j] = *(const bf16x8*)&L[4096 + (((qc * 4 + j) * 2 + s) * 64 + lane) * 8];
#pragma unroll
      for (int i = 0; i < 2; ++i)
#pragma unroll
        for (int j = 0; j < 4; ++j)
          acc[i][j] = __builtin_amdgcn_mfma_f32_16x16x32_bf16(af[i], bfr[j], acc[i][j], 0, 0, 0);
    }
    __syncthreads();
    bsel ^= 1;
  }

  const float* X = z ? x1 : x0;
  float* O = z ? out1 : out0;
#pragma unroll
  for (int j = 0; j < 4; ++j) {
    int col = col0 + qc * 64 + j * 16 + l15;
    float bb = b3[col];
#pragma unroll
    for (int i = 0; i < 2; ++i)
#pragma unroll
      for (int r = 0; r < 4; ++r) {
        size_t grow = row0 + qr * 32 + i * 16 + qd * 4 + r;
        O[grow * 256 + col] = X[grow * 256 + col] + acc[i][j][r] + bb;
      }
  }
}

// ---------------------------------------------------------------------------
// Workspace (byte offsets), total 67 MB:
//   0/4: x0b,x1b | 8: Wqvt,W1t,W3t | 9: biases | 10/14: qk | 18/22: vt
//   26/30: m0b,m1b | y0b/y1b overlay 10/18 | 34-66: Opart[4] | 66: lpart
//   66M+512K: tickets (4 KB) | 66M+516K: lnsum/lnsq (128 KB)
// ---------------------------------------------------------------------------
extern "C" void kernel_launch(void* const* d_in, const int* in_sizes, int n_in,
                              void* d_out, int out_size, void* d_ws,
                              size_t ws_size, hipStream_t stream) {
  const float* x0   = (const float*)d_in[0];
  const float* x1   = (const float*)d_in[1];
  const float* Wqk  = (const float*)d_in[2];
  const float* bqk  = (const float*)d_in[3];
  const float* Wv   = (const float*)d_in[4];
  const float* bv   = (const float*)d_in[5];
  const float* Wout = (const float*)d_in[6];
  const float* bout = (const float*)d_in[7];
  const float* W0   = (const float*)d_in[8];
  const float* b0   = (const float*)d_in[9];
  const float* lns  = (const float*)d_in[10];
  const float* lnb  = (const float*)d_in[11];
  const float* W3   = (const float*)d_in[12];
  const float* b3   = (const float*)d_in[13];

  char* ws = (char*)d_ws;
  const size_t MB = 1024 * 1024;
  us* x0b  = (us*)(ws + 0 * MB);
  us* x1b  = (us*)(ws + 4 * MB);
  us* Wqvt = (us*)(ws + 8 * MB);
  us* W1t  = (us*)(ws + 8 * MB + 262144);
  us* W3t  = (us*)(ws + 8 * MB + 786432);
  float* bias_qv = (float*)(ws + 9 * MB);
  float* bias1   = (float*)(ws + 9 * MB + 4096);
  us* qk0b = (us*)(ws + 10 * MB);
  us* qk1b = (us*)(ws + 14 * MB);
  us* vt0  = (us*)(ws + 18 * MB);
  us* vt1  = (us*)(ws + 22 * MB);
  us* m0b  = (us*)(ws + 26 * MB);
  us* m1b  = (us*)(ws + 30 * MB);
  us* y0b  = (us*)(ws + 10 * MB);  // overlay qk (dead after flash)
  us* y1b  = (us*)(ws + 18 * MB);  // overlay vt (dead after flash)
  float* Opart = (float*)(ws + 34 * MB);
  float* lpart = (float*)(ws + 66 * MB);
  int* tickets = (int*)(ws + 66 * MB + 524288);
  float* lnsum = (float*)(ws + 66 * MB + 528384);
  float* lnsq  = lnsum + 2 * MROWS;
  float* zbase = (float*)(ws + 66 * MB + 524288);  // tickets + stats region
  float* out0 = (float*)d_out;
  float* out1 = out0 + (size_t)MROWS * DMODEL;

  dim3 blk(256);

  prep_k<<<dim3(5924), blk, 0, stream>>>(x0, x1, Wqk, Wv, W0, W3, Wout,
                                         bqk, bv, b0, bout,
                                         x0b, x1b, Wqvt, W1t, W3t,
                                         bias_qv, bias1, zbase);

  // QK+V projection fused (N=512)
  gemm6<0><<<dim3(64, 4, 2), blk, 0, stream>>>(
      x0b, x1b, nullptr, nullptr, Wqvt, bias_qv,
      qk0b, qk1b, vt0, vt1, 256, nullptr, nullptr);

  // Bidirectional cross attention + in-kernel combine
  flash_v8<<<dim3(32, 4, 8), blk, 0, stream>>>(qk0b, qk1b, vt0, vt1,
                                               Opart, lpart, m0b, m1b, tickets);

  // FFN1 (out-proj folded) + LN-stats accumulation
  gemm6<1><<<dim3(64, 4, 2), blk, 0, stream>>>(
      x0b, x1b, m0b, m1b, W1t, bias1,
      y0b, y1b, nullptr, nullptr, 512, lnsum, lnsq);

  // FFN2 with fused LN+GELU staging: out = x + gelu(LN(y)) @ W3 + b3
  ffn2_k<<<dim3(128, 2, 2), blk, 0, stream>>>(
      y0b, y1b, W3t, b3, x0, x1, out0, out1, lnsum, lnsq, lns, lnb);
}

// Round 10
// 251.953 us; speedup vs baseline: 1.6298x; 1.6298x over previous
//
#include <hip/hip_runtime.h>
#include <math.h>

#define BATCH 4
#define SEQ 2048
#define DMODEL 256
#define NH 4
#define HD 64
#define MROWS 8192
#define QKSCALE 0.4246608905f  // sqrt(0.125 * log2(e)): qk pre-scaled => exp2 direct

typedef short bf16x8 __attribute__((ext_vector_type(8)));
typedef float f32x4 __attribute__((ext_vector_type(4)));
typedef unsigned short us;

#if __has_builtin(__builtin_amdgcn_exp2f)
#define EXP2(x) __builtin_amdgcn_exp2f(x)
#else
#define EXP2(x) exp2f(x)
#endif

__device__ __forceinline__ us f2bf(float x) {  // RNE
  union { float f; unsigned int u; } v;
  v.f = x;
  unsigned int r = (v.u + 0x7FFF + ((v.u >> 16) & 1)) >> 16;
  return (us)r;
}
__device__ __forceinline__ float bf2f(us u) {
  union { unsigned int u; float f; } v;
  v.u = ((unsigned int)u) << 16;
  return v.f;
}
__device__ __forceinline__ unsigned int fbits(float x) {
  union { float f; unsigned int u; } v;
  v.f = x;
  return v.u;
}
// v_perm pack: [bf16_trunc(lo) | bf16_trunc(hi)<<16] in one instruction.
__device__ __forceinline__ unsigned int pk2bf(float lo, float hi) {
  return __builtin_amdgcn_perm(fbits(hi), fbits(lo), 0x07060302u);
}
// Async global->LDS DMA, 16B/lane; lane i lands at base + i*16.
__device__ __forceinline__ void dma16(const void* g, void* l) {
  auto gp = (const __attribute__((address_space(1))) unsigned int*)(unsigned long long)(uintptr_t)g;
  auto lp = (__attribute__((address_space(3))) unsigned int*)(unsigned int)(uintptr_t)l;
  __builtin_amdgcn_global_load_lds(gp, lp, 16, 0, 0);
}

// ---------------------------------------------------------------------------
// prep_k: casts + weight transposes + out-proj fold + zero ln-stats.
// ---------------------------------------------------------------------------
__global__ __launch_bounds__(256) void prep_k(
    const float* __restrict__ x0, const float* __restrict__ x1,
    const float* __restrict__ Wqk, const float* __restrict__ Wv,
    const float* __restrict__ W0, const float* __restrict__ W3,
    const float* __restrict__ Wout,
    const float* __restrict__ bqk, const float* __restrict__ bv,
    const float* __restrict__ b0, const float* __restrict__ bout,
    us* __restrict__ x0b, us* __restrict__ x1b,
    us* __restrict__ Wqvt, us* __restrict__ W1t, us* __restrict__ W3t,
    float* __restrict__ bias_qv, float* __restrict__ bias1,
    float* __restrict__ zbase) {
  const int bid = blockIdx.x, t = threadIdx.x;
  if (bid < 4096) {
    const int n4 = (MROWS * DMODEL) / 4;
    int i = bid * 256 + t;
    const float* src = (i < n4) ? x0 : x1;
    us* dst = (i < n4) ? x0b : x1b;
    int j = (i < n4) ? i : i - n4;
    float4 v = *(const float4*)&src[j * 4];
    ushort4 o = {f2bf(v.x), f2bf(v.y), f2bf(v.z), f2bf(v.w)};
    *(ushort4*)&dst[j * 4] = o;
  } else if (bid < 5634) {
    int gid = (bid - 4096) * 256 + t;
    if (gid < 65536) {
      int k = gid >> 8, j = gid & 255;
      Wqvt[j * 256 + k] = f2bf(Wqk[gid]);
    } else if (gid < 131072) {
      int i = gid - 65536;
      int k = i >> 8, j = i & 255;
      Wqvt[(256 + j) * 256 + k] = f2bf(Wv[i]);
    } else if (gid < 262144) {
      int i = gid - 131072;
      int k = i >> 9, j = i & 511;
      W1t[j * 512 + k] = f2bf(W0[i]);
    } else if (gid < 393216) {
      int i = gid - 262144;
      int k = i >> 8, j = i & 255;
      W3t[j * 512 + k] = f2bf(W3[i]);
    } else if (gid < 393728) {
      int j = gid - 393216;
      bias_qv[j] = (j < 256) ? bqk[j] : bv[j - 256];
    }
  } else if (bid < 5891) {
    int i = bid - 5634;  // [0,257)
    if (i < 256) {
      float a0 = 0.f, a1 = 0.f;
      for (int k0 = 0; k0 < 256; k0 += 8) {
        float wk[8], r0[8], r1[8];
#pragma unroll
        for (int u = 0; u < 8; ++u) {
          wk[u] = Wout[i * 256 + k0 + u];
          const float* row = &W0[(size_t)(256 + k0 + u) * 512];
          r0[u] = row[t];
          r1[u] = row[t + 256];
        }
#pragma unroll
        for (int u = 0; u < 8; ++u) { a0 += wk[u] * r0[u]; a1 += wk[u] * r1[u]; }
      }
      W1t[t * 512 + 256 + i] = f2bf(a0);
      W1t[(t + 256) * 512 + 256 + i] = f2bf(a1);
    } else {
      float a0 = b0[t], a1 = b0[t + 256];
      for (int k = 0; k < 256; ++k) {
        float bk = bout[k];
        const float* row = &W0[(size_t)(256 + k) * 512];
        a0 += bk * row[t];
        a1 += bk * row[t + 256];
      }
      bias1[t] = a0;
      bias1[t + 256] = a1;
    }
  } else {
    int i = (bid - 5891) * 256 + t;
    if (i * 4 < 33792) {
      float4 zz = {0.f, 0.f, 0.f, 0.f};
      *(float4*)&zbase[i * 4] = zz;
    }
  }
}

// ---------------------------------------------------------------------------
// gemm7: MFMA bf16 GEMM, 64x128 tile, dbuf DMA staging (48 KB LDS ->
// 3 blocks/CU, 12 waves/CU), XCD remap (4 col-tiles of one A-tile colocate).
// 4 waves as 2x2 quadrants of 32x64. Grid (128, 4, 2) = 1024 blocks.
//   MODE 0 (QV, N=512): coltile<2 -> qk *QKSCALE; >=2 -> Vt transposed
//   MODE 1 (FFN1, N=512): A = concat(Ax, Am); bf16 out + LN-stats atomics
// ---------------------------------------------------------------------------
template <int MODE>
__global__ __launch_bounds__(256) void gemm7(
    const us* __restrict__ A0, const us* __restrict__ A1,
    const us* __restrict__ Am0, const us* __restrict__ Am1,
    const us* __restrict__ Wt, const float* __restrict__ bias,
    void* __restrict__ C0_, void* __restrict__ C1_,
    void* __restrict__ V0_, void* __restrict__ V1_, int K,
    float* __restrict__ lnsum, float* __restrict__ lnsq) {
  constexpr int BUFS = 12288;  // shorts: A 4096 + B 8192 (24 KB)
  __shared__ us lds[2 * BUFS];  // 48 KB

  const int t = threadIdx.x, w = t >> 6, lane = t & 63;
  const int qd = lane >> 4, l15 = lane & 15;

  // XCD remap: group the 4 col-tiles of one (bx,z) on one XCD.
  const int flat = blockIdx.x + 128 * (blockIdx.y + 4 * blockIdx.z);
  const int xcd = flat & 7, slot = flat >> 3;      // slot in [0,128)
  const int xz = xcd * 32 + (slot >> 2);           // [0,256)
  const int bx = xz & 127, z = xz >> 7, coltile = slot & 3;
  const int row0 = bx * 64, col0 = coltile * 128;

  const us* Ax = z ? A1 : A0;
  const us* Am = z ? Am1 : Am0;
  const int qr = w >> 1, qc = w & 1;

  f32x4 acc[2][4];
#pragma unroll
  for (int i = 0; i < 2; ++i)
#pragma unroll
    for (int j = 0; j < 4; ++j) acc[i][j] = (f32x4){0.f, 0.f, 0.f, 0.f};

  const int NK = K >> 6;
  // Prologue: k-tile 0 -> buffer 0. 24 granules (8 A + 16 B), 6 per wave.
#pragma unroll
  for (int pp = 0; pp < 6; ++pp) {
    int g = pp * 4 + w;
    const us* src;
    int dstoff;
    if (g < 8) {
      int tm = g >> 1, s = g & 1;
      src = &Ax[(size_t)(row0 + tm * 16 + l15) * ((MODE == 1) ? 256 : K) + s * 32 + qd * 8];
      dstoff = g * 512;
    } else {
      int gb = g - 8, tn = gb >> 1, s = gb & 1;
      src = &Wt[(size_t)(col0 + tn * 16 + l15) * K + s * 32 + qd * 8];
      dstoff = 4096 + gb * 512;
    }
    dma16(src, &lds[dstoff]);
  }
  __syncthreads();

  int bsel = 0;
  for (int it = 0; it < NK; ++it) {
    if (it + 1 < NK) {
      int k0 = (it + 1) << 6;
#pragma unroll
      for (int pp = 0; pp < 6; ++pp) {
        int g = pp * 4 + w;
        const us* src;
        int dstoff;
        if (g < 8) {
          int tm = g >> 1, s = g & 1;
          const us* Ap = Ax;
          int kk = k0 + s * 32 + qd * 8, lda = K;
          if (MODE == 1) {
            Ap = (k0 < 256) ? Ax : Am;
            kk &= 255;
            lda = 256;
          }
          src = &Ap[(size_t)(row0 + tm * 16 + l15) * lda + kk];
          dstoff = g * 512;
        } else {
          int gb = g - 8, tn = gb >> 1, s = gb & 1;
          src = &Wt[(size_t)(col0 + tn * 16 + l15) * K + k0 + s * 32 + qd * 8];
          dstoff = 4096 + gb * 512;
        }
        dma16(src, &lds[(bsel ^ 1) * BUFS + dstoff]);
      }
    }
    const us* L = &lds[bsel * BUFS];
#pragma unroll
    for (int s = 0; s < 2; ++s) {
      bf16x8 af[2], bfr[4];
#pragma unroll
      for (int i = 0; i < 2; ++i)
        af[i] = *(const bf16x8*)&L[(((qr * 2 + i) * 2 + s) * 64 + lane) * 8];
#pragma unroll
      for (int j = 0; j < 4; ++j)
        bfr[j] = *(const bf16x8*)&L[4096 + (((qc * 4 + j) * 2 + s) * 64 + lane) * 8];
#pragma unroll
      for (int i = 0; i < 2; ++i)
#pragma unroll
        for (int j = 0; j < 4; ++j)
          acc[i][j] = __builtin_amdgcn_mfma_f32_16x16x32_bf16(af[i], bfr[j], acc[i][j], 0, 0, 0);
    }
    __syncthreads();
    bsel ^= 1;
  }

  // Epilogues. C-layout: row = row0 + qr*32 + i*16 + qd*4 + r,
  //                      col = col0 + qc*64 + j*16 + l15.
  if (MODE == 0 && coltile >= 2) {
    // Vt transposed via LDS bounce: 128 cols x 64 rows, stride 66.
    int base = qc * 4224;
#pragma unroll
    for (int j = 0; j < 4; ++j) {
      int col = col0 + qc * 64 + j * 16 + l15;
      float bb = bias[col];
#pragma unroll
      for (int i = 0; i < 2; ++i)
#pragma unroll
        for (int r = 0; r < 4; ++r)
          lds[base + (j * 16 + l15) * 66 + (qr * 32 + i * 16 + qd * 4 + r)] =
              f2bf(acc[i][j][r] + bb);
    }
    __syncthreads();
    us* Vt = (us*)(z ? V1_ : V0_);
    int b_ = row0 >> 11, seq0 = row0 & 2047;
    for (int c = t; c < 1024; c += 256) {
      int dloc = c >> 3, scc = c & 7;  // dloc: 128 local cols, scc: 8-chunk
      int hh = dloc >> 6;
      int h = (coltile - 2) * 2 + hh, hd = dloc & 63;
      uint4 d = *(const uint4*)&lds[dloc * 66 + scc * 8];
      *(uint4*)&Vt[((size_t)(b_ * NH + h) * HD + hd) * SEQ + seq0 + scc * 8] = d;
    }
    return;
  }

  // bf16 natural out via LDS bounce (64 rows x 128 cols, stride 132).
#pragma unroll
  for (int j = 0; j < 4; ++j) {
    int cl = qc * 64 + j * 16 + l15;
    float bb = bias[col0 + cl];
#pragma unroll
    for (int i = 0; i < 2; ++i)
#pragma unroll
      for (int r = 0; r < 4; ++r) {
        float v = acc[i][j][r] + bb;
        if (MODE == 0) v *= QKSCALE;
        lds[(qr * 32 + i * 16 + qd * 4 + r) * 132 + cl] = f2bf(v);
      }
  }
  __syncthreads();
  us* C = (us*)(z ? C1_ : C0_);
  const int ldc = (MODE == 0) ? 256 : 512;
  for (int c = t; c < 1024; c += 256) {
    int rl = c >> 4, c8 = (c & 15) * 8;
    uint4 d = *(const uint4*)&lds[rl * 132 + c8];
    *(uint4*)&C[(size_t)(row0 + rl) * ldc + col0 + c8] = d;
  }

  if (MODE == 1) {
    // LN stats: per-row sum/sumsq of this 128-col slice; 4 threads/row.
    int rl = t >> 2, q4 = t & 3;
    float s1 = 0.f, s2 = 0.f;
#pragma unroll
    for (int c = 0; c < 4; ++c) {
      uint4 d = *(const uint4*)&lds[rl * 132 + q4 * 32 + c * 8];
      unsigned int uu[4] = {d.x, d.y, d.z, d.w};
#pragma unroll
      for (int i = 0; i < 4; ++i) {
        float a = bf2f((us)(uu[i] & 0xFFFF));
        float b = bf2f((us)(uu[i] >> 16));
        s1 += a + b;
        s2 += a * a + b * b;
      }
    }
    s1 += __shfl_xor(s1, 1);
    s2 += __shfl_xor(s2, 1);
    s1 += __shfl_xor(s1, 2);
    s2 += __shfl_xor(s2, 2);
    if (q4 == 0) {
      atomicAdd(&lnsum[z * MROWS + row0 + rl], s1);
      atomicAdd(&lnsq[z * MROWS + row0 + rl], s2);
    }
  }
}

// ---------------------------------------------------------------------------
// flash_v7 (the proven 51 us version): register-P MFMA flash, kv-split x2,
// both dirs, dbuf DMA prefetch, v_perm P-packing, XCD remap.
// ---------------------------------------------------------------------------
__global__ __launch_bounds__(256) void flash_v7(
    const us* __restrict__ qk0, const us* __restrict__ qk1,
    const us* __restrict__ vt0, const us* __restrict__ vt1,
    float* __restrict__ Opart, float* __restrict__ lpart) {
  __shared__ us lds[16384];  // 2 x 16KB buffers
  const int t = threadIdx.x, w = t >> 6, lane = t & 63;
  const int qd = lane >> 4, l15 = lane & 15;

  const int flat = blockIdx.x + 32 * (blockIdx.y + 4 * blockIdx.z);
  const int xcd = flat & 7, slot = flat >> 3;
  const int combo = (xcd << 2) + (slot >> 5);
  const int qs = slot & 31;
  const int qt = qs & 15, half = qs >> 4;
  const int dir = combo >> 4, bh = combo & 15, b = bh >> 2, h = bh & 3;

  const us* Qb = dir ? qk1 : qk0;
  const us* Kb = dir ? qk0 : qk1;
  const us* Vt = dir ? vt0 : vt1;
  float* Op = Opart + (size_t)(dir * 2 + half) * (MROWS * DMODEL);
  float* lp = lpart + ((size_t)(dir * 2 + half) * NH + h) * MROWS;
  const size_t qrow0 = (size_t)b * SEQ + (size_t)qt * 128;
  const int hoff = h * HD;
  const us* vtb = Vt + (size_t)(b * NH + h) * HD * SEQ;
  const int kt0 = half * 16;

  const us* sp[4];
  int sstr[4];
#pragma unroll
  for (int pp = 0; pp < 4; ++pp) {
    int g = pp * 4 + w;
    if (g < 8) {
      int tk = g >> 1, s = g & 1;
      int kvl = (tk >> 1) * 32 + (l15 >> 2) * 8 + (tk & 1) * 4 + (l15 & 3);  // pi
      sp[pp] = &Kb[(size_t)(b * SEQ + kt0 * 64 + kvl) * DMODEL + hoff + s * 32 + qd * 8];
      sstr[pp] = 64 * DMODEL;
    } else {
      int td = (g - 8) >> 1, s = g & 1;
      sp[pp] = &vtb[(size_t)(td * 16 + l15) * SEQ + kt0 * 64 + s * 32 + qd * 8];
      sstr[pp] = 64;
    }
  }

  bf16x8 qf[2][2];
#pragma unroll
  for (int qh = 0; qh < 2; ++qh)
#pragma unroll
    for (int s = 0; s < 2; ++s)
      qf[qh][s] = *(const bf16x8*)&Qb[(qrow0 + w * 32 + qh * 16 + l15) * DMODEL + hoff + s * 32 + qd * 8];

  f32x4 Oacc[2][4];
#pragma unroll
  for (int qh = 0; qh < 2; ++qh)
#pragma unroll
    for (int td = 0; td < 4; ++td) Oacc[qh][td] = (f32x4){0.f, 0.f, 0.f, 0.f};
  float l_lane[2] = {0.f, 0.f};

#pragma unroll
  for (int pp = 0; pp < 4; ++pp) {
    dma16(sp[pp], &lds[(pp * 4 + w) * 512]);
    sp[pp] += sstr[pp];
  }
  __syncthreads();

  int bsel = 0;
  for (int it = 0; it < 16; ++it) {
    if (it < 15) {
#pragma unroll
      for (int pp = 0; pp < 4; ++pp) {
        dma16(sp[pp], &lds[(bsel ^ 1) * 8192 + (pp * 4 + w) * 512]);
        sp[pp] += sstr[pp];
      }
    }
    const us* L = &lds[bsel * 8192];

    bf16x8 kf[4][2], vf[4][2];
#pragma unroll
    for (int tk = 0; tk < 4; ++tk)
#pragma unroll
      for (int s = 0; s < 2; ++s) {
        kf[tk][s] = *(const bf16x8*)&L[((tk * 2 + s) * 64 + lane) * 8];
        vf[tk][s] = *(const bf16x8*)&L[((8 + tk * 2 + s) * 64 + lane) * 8];
      }

#pragma unroll
    for (int qh = 0; qh < 2; ++qh) {
      f32x4 S[4];
#pragma unroll
      for (int tk = 0; tk < 4; ++tk) {
        f32x4 a = {0.f, 0.f, 0.f, 0.f};
        a = __builtin_amdgcn_mfma_f32_16x16x32_bf16(kf[tk][0], qf[qh][0], a, 0, 0, 0);
        a = __builtin_amdgcn_mfma_f32_16x16x32_bf16(kf[tk][1], qf[qh][1], a, 0, 0, 0);
        S[tk] = a;
      }
      float p[4][4];
      float rs = 0.f;
#pragma unroll
      for (int tk = 0; tk < 4; ++tk)
#pragma unroll
        for (int r = 0; r < 4; ++r) {
          float pv = EXP2(S[tk][r]);
          p[tk][r] = pv;
          rs += pv;
        }
      l_lane[qh] += rs;
      union { bf16x8 v; unsigned int u[4]; } pk0, pk1;
      pk0.u[0] = pk2bf(p[0][0], p[0][1]);
      pk0.u[1] = pk2bf(p[0][2], p[0][3]);
      pk0.u[2] = pk2bf(p[1][0], p[1][1]);
      pk0.u[3] = pk2bf(p[1][2], p[1][3]);
      pk1.u[0] = pk2bf(p[2][0], p[2][1]);
      pk1.u[1] = pk2bf(p[2][2], p[2][3]);
      pk1.u[2] = pk2bf(p[3][0], p[3][1]);
      pk1.u[3] = pk2bf(p[3][2], p[3][3]);
#pragma unroll
      for (int td = 0; td < 4; ++td) {
        Oacc[qh][td] = __builtin_amdgcn_mfma_f32_16x16x32_bf16(pk0.v, vf[td][0], Oacc[qh][td], 0, 0, 0);
        Oacc[qh][td] = __builtin_amdgcn_mfma_f32_16x16x32_bf16(pk1.v, vf[td][1], Oacc[qh][td], 0, 0, 0);
      }
    }
    __syncthreads();
    bsel ^= 1;
  }

#pragma unroll
  for (int qh = 0; qh < 2; ++qh) {
    float l = l_lane[qh];
    l += __shfl_xor(l, 16);
    l += __shfl_xor(l, 32);
    if (qd == 0) lp[qrow0 + w * 32 + qh * 16 + l15] = l;
#pragma unroll
    for (int r = 0; r < 4; ++r) {
      size_t row = qrow0 + w * 32 + qh * 16 + qd * 4 + r;
#pragma unroll
      for (int td = 0; td < 4; ++td)
        Op[row * DMODEL + hoff + td * 16 + l15] = Oacc[qh][td][r];
    }
  }
}

// ---------------------------------------------------------------------------
// Merge kv-halves: m = (Oa + Ob) / (la + lb), bf16 out.
// ---------------------------------------------------------------------------
__global__ __launch_bounds__(256) void combine_k(
    const float* __restrict__ Opart, const float* __restrict__ lpart,
    us* __restrict__ m0b, us* __restrict__ m1b) {
  int gid = blockIdx.x * 256 + threadIdx.x;
  int dir = gid >= (MROWS * DMODEL / 4);
  int idx = gid - dir * (MROWS * DMODEL / 4);
  int row = idx >> 6;
  int c4 = (idx & 63) << 2;
  int h = c4 >> 6;
  const float* Oa = Opart + (size_t)(dir * 2 + 0) * (MROWS * DMODEL);
  const float* Ob = Opart + (size_t)(dir * 2 + 1) * (MROWS * DMODEL);
  float la = lpart[((size_t)(dir * 2 + 0) * NH + h) * MROWS + row];
  float lb = lpart[((size_t)(dir * 2 + 1) * NH + h) * MROWS + row];
  float inv = 1.0f / (la + lb);
  float4 a = *(const float4*)&Oa[(size_t)row * DMODEL + c4];
  float4 bv = *(const float4*)&Ob[(size_t)row * DMODEL + c4];
  us* m = dir ? m1b : m0b;
  ushort4 o = {f2bf((a.x + bv.x) * inv), f2bf((a.y + bv.y) * inv),
               f2bf((a.z + bv.z) * inv), f2bf((a.w + bv.w) * inv)};
  *(ushort4*)&m[(size_t)row * DMODEL + c4] = o;
}

// ---------------------------------------------------------------------------
// ffn2_k: out = x + gelu(LN(y)) @ W3 + b3, LN+GELU during A-staging.
// Tile 64x128, grid (128,2,2) = 512 blocks.
// ---------------------------------------------------------------------------
__global__ __launch_bounds__(256) void ffn2_k(
    const us* __restrict__ y0b, const us* __restrict__ y1b,
    const us* __restrict__ W3t, const float* __restrict__ b3,
    const float* __restrict__ x0, const float* __restrict__ x1,
    float* __restrict__ out0, float* __restrict__ out1,
    const float* __restrict__ lnsum, const float* __restrict__ lnsq,
    const float* __restrict__ sc, const float* __restrict__ bi) {
  constexpr int BUFS = 12288;  // shorts: A 4096 + B 8192
  __shared__ us lds[2 * BUFS];  // 48 KB
  const int t = threadIdx.x, w = t >> 6, lane = t & 63;
  const int qd = lane >> 4, l15 = lane & 15;

  const int flat = blockIdx.x + 128 * (blockIdx.y + 2 * blockIdx.z);
  const int xcd = flat & 7, slot = flat >> 3;
  const int xz = xcd * 32 + (slot >> 1);
  const int bx = xz & 127, z = xz >> 7, ct = slot & 1;
  const int row0 = bx * 64, col0 = ct * 128;

  const us* Y = z ? y1b : y0b;
  const float* lsum = lnsum + z * MROWS;
  const float* lsq = lnsq + z * MROWS;
  const int qr = w >> 1, qc = w & 1;

  f32x4 acc[2][4];
#pragma unroll
  for (int i = 0; i < 2; ++i)
#pragma unroll
    for (int j = 0; j < 4; ++j) acc[i][j] = (f32x4){0.f, 0.f, 0.f, 0.f};

  auto stage = [&](int k0, us* buf) {
#pragma unroll
    for (int pp = 0; pp < 4; ++pp) {
      int gb = pp * 4 + w;
      int tn = gb >> 1, s = gb & 1;
      dma16(&W3t[(size_t)(col0 + tn * 16 + l15) * 512 + k0 + s * 32 + qd * 8],
            &buf[4096 + gb * 512]);
    }
#pragma unroll
    for (int pp = 0; pp < 2; ++pp) {
      int g = pp * 4 + w;
      int tm = g >> 1, s = g & 1;
      int row = row0 + tm * 16 + l15;
      int kk = k0 + s * 32 + qd * 8;
      uint4 d = *(const uint4*)&Y[(size_t)row * 512 + kk];
      float mu = lsum[row] * (1.0f / 512.0f);
      float vr = lsq[row] * (1.0f / 512.0f) - mu * mu;
      float rstd = rsqrtf(vr + 1e-5f);
      unsigned int uu[4] = {d.x, d.y, d.z, d.w};
      unsigned int ou[4];
#pragma unroll
      for (int i = 0; i < 4; ++i) {
        int k_ = kk + 2 * i;
        float a = bf2f((us)(uu[i] & 0xFFFF));
        float bq = bf2f((us)(uu[i] >> 16));
        float g0 = (a - mu) * rstd * sc[k_] + bi[k_];
        float g1 = (bq - mu) * rstd * sc[k_ + 1] + bi[k_ + 1];
        g0 = 0.5f * g0 * (1.0f + erff(g0 * 0.70710678118654752f));
        g1 = 0.5f * g1 * (1.0f + erff(g1 * 0.70710678118654752f));
        ou[i] = pk2bf(g0, g1);
      }
      uint4 o = {ou[0], ou[1], ou[2], ou[3]};
      *(uint4*)&buf[g * 512 + lane * 8] = o;
    }
  };

  stage(0, lds);
  __syncthreads();
  int bsel = 0;
  for (int it = 0; it < 8; ++it) {
    if (it < 7) stage((it + 1) * 64, &lds[(bsel ^ 1) * BUFS]);
    const us* L = &lds[bsel * BUFS];
#pragma unroll
    for (int s = 0; s < 2; ++s) {
      bf16x8 af[2], bfr[4];
#pragma unroll
      for (int i = 0; i < 2; ++i)
        af[i] = *(const bf16x8*)&L[(((qr * 2 + i) * 2 + s) * 64 + lane) * 8];
#pragma unroll
      for (int j = 0; j < 4; ++j)
        bfr[j] = *(const bf16x8*)&L[4096 + (((qc * 4 + j) * 2 + s) * 64 + lane) * 8];
#pragma unroll
      for (int i = 0; i < 2; ++i)
#pragma unroll
        for (int j = 0; j < 4; ++j)
          acc[i][j] = __builtin_amdgcn_mfma_f32_16x16x32_bf16(af[i], bfr[j], acc[i][j], 0, 0, 0);
    }
    __syncthreads();
    bsel ^= 1;
  }

  const float* X = z ? x1 : x0;
  float* O = z ? out1 : out0;
#pragma unroll
  for (int j = 0; j < 4; ++j) {
    int col = col0 + qc * 64 + j * 16 + l15;
    float bb = b3[col];
#pragma unroll
    for (int i = 0; i < 2; ++i)
#pragma unroll
      for (int r = 0; r < 4; ++r) {
        size_t grow = row0 + qr * 32 + i * 16 + qd * 4 + r;
        O[grow * 256 + col] = X[grow * 256 + col] + acc[i][j][r] + bb;
      }
  }
}

// ---------------------------------------------------------------------------
// Workspace (byte offsets), total 67 MB:
//   0/4: x0b,x1b | 8: Wqvt,W1t,W3t | 9: biases | 10/14: qk | 18/22: vt
//   26/30: m0b,m1b | y0b/y1b overlay 10/18 | 34-66: Opart[4] | 66: lpart
//   66M+512K: zero region (tickets legacy + lnsum/lnsq)
// ---------------------------------------------------------------------------
extern "C" void kernel_launch(void* const* d_in, const int* in_sizes, int n_in,
                              void* d_out, int out_size, void* d_ws,
                              size_t ws_size, hipStream_t stream) {
  const float* x0   = (const float*)d_in[0];
  const float* x1   = (const float*)d_in[1];
  const float* Wqk  = (const float*)d_in[2];
  const float* bqk  = (const float*)d_in[3];
  const float* Wv   = (const float*)d_in[4];
  const float* bv   = (const float*)d_in[5];
  const float* Wout = (const float*)d_in[6];
  const float* bout = (const float*)d_in[7];
  const float* W0   = (const float*)d_in[8];
  const float* b0   = (const float*)d_in[9];
  const float* lns  = (const float*)d_in[10];
  const float* lnb  = (const float*)d_in[11];
  const float* W3   = (const float*)d_in[12];
  const float* b3   = (const float*)d_in[13];

  char* ws = (char*)d_ws;
  const size_t MB = 1024 * 1024;
  us* x0b  = (us*)(ws + 0 * MB);
  us* x1b  = (us*)(ws + 4 * MB);
  us* Wqvt = (us*)(ws + 8 * MB);
  us* W1t  = (us*)(ws + 8 * MB + 262144);
  us* W3t  = (us*)(ws + 8 * MB + 786432);
  float* bias_qv = (float*)(ws + 9 * MB);
  float* bias1   = (float*)(ws + 9 * MB + 4096);
  us* qk0b = (us*)(ws + 10 * MB);
  us* qk1b = (us*)(ws + 14 * MB);
  us* vt0  = (us*)(ws + 18 * MB);
  us* vt1  = (us*)(ws + 22 * MB);
  us* m0b  = (us*)(ws + 26 * MB);
  us* m1b  = (us*)(ws + 30 * MB);
  us* y0b  = (us*)(ws + 10 * MB);  // overlay qk (dead after flash)
  us* y1b  = (us*)(ws + 18 * MB);  // overlay vt (dead after flash)
  float* Opart = (float*)(ws + 34 * MB);
  float* lpart = (float*)(ws + 66 * MB);
  float* zbase = (float*)(ws + 66 * MB + 524288);
  float* lnsum = (float*)(ws + 66 * MB + 528384);
  float* lnsq  = lnsum + 2 * MROWS;
  float* out0 = (float*)d_out;
  float* out1 = out0 + (size_t)MROWS * DMODEL;

  dim3 blk(256);

  prep_k<<<dim3(5924), blk, 0, stream>>>(x0, x1, Wqk, Wv, W0, W3, Wout,
                                         bqk, bv, b0, bout,
                                         x0b, x1b, Wqvt, W1t, W3t,
                                         bias_qv, bias1, zbase);

  // QK+V projection fused (N=512): coltile 0-1 qk scaled, 2-3 vt transposed
  gemm7<0><<<dim3(128, 4, 2), blk, 0, stream>>>(
      x0b, x1b, nullptr, nullptr, Wqvt, bias_qv,
      qk0b, qk1b, vt0, vt1, 256, nullptr, nullptr);

  // Bidirectional cross attention (kv-split x2), then merge
  flash_v7<<<dim3(32, 4, 8), blk, 0, stream>>>(qk0b, qk1b, vt0, vt1, Opart, lpart);
  combine_k<<<dim3(4096), blk, 0, stream>>>(Opart, lpart, m0b, m1b);

  // FFN1 (out-proj folded) + LN-stats accumulation
  gemm7<1><<<dim3(128, 4, 2), blk, 0, stream>>>(
      x0b, x1b, m0b, m1b, W1t, bias1,
      y0b, y1b, nullptr, nullptr, 512, lnsum, lnsq);

  // FFN2 with fused LN+GELU staging: out = x + gelu(LN(y)) @ W3 + b3
  ffn2_k<<<dim3(128, 2, 2), blk, 0, stream>>>(
      y0b, y1b, W3t, b3, x0, x1, out0, out1, lnsum, lnsq, lns, lnb);
}

// Round 11
// 243.336 us; speedup vs baseline: 1.6875x; 1.0354x over previous
//
#include <hip/hip_runtime.h>
#include <math.h>

#define BATCH 4
#define SEQ 2048
#define DMODEL 256
#define NH 4
#define HD 64
#define MROWS 8192
#define QKSCALE 0.4246608905f  // sqrt(0.125 * log2(e)): qk pre-scaled => exp2 direct

typedef short bf16x8 __attribute__((ext_vector_type(8)));
typedef float f32x4 __attribute__((ext_vector_type(4)));
typedef unsigned short us;

#if __has_builtin(__builtin_amdgcn_exp2f)
#define EXP2(x) __builtin_amdgcn_exp2f(x)
#else
#define EXP2(x) exp2f(x)
#endif

__device__ __forceinline__ us f2bf(float x) {  // RNE
  union { float f; unsigned int u; } v;
  v.f = x;
  unsigned int r = (v.u + 0x7FFF + ((v.u >> 16) & 1)) >> 16;
  return (us)r;
}
__device__ __forceinline__ float bf2f(us u) {
  union { unsigned int u; float f; } v;
  v.u = ((unsigned int)u) << 16;
  return v.f;
}
__device__ __forceinline__ unsigned int fbits(float x) {
  union { float f; unsigned int u; } v;
  v.f = x;
  return v.u;
}
// v_perm pack: [bf16_trunc(lo) | bf16_trunc(hi)<<16] in one instruction.
__device__ __forceinline__ unsigned int pk2bf(float lo, float hi) {
  return __builtin_amdgcn_perm(fbits(hi), fbits(lo), 0x07060302u);
}
// Async global->LDS DMA, 16B/lane (kept for flash only — measured win there).
__device__ __forceinline__ void dma16(const void* g, void* l) {
  auto gp = (const __attribute__((address_space(1))) unsigned int*)(unsigned long long)(uintptr_t)g;
  auto lp = (__attribute__((address_space(3))) unsigned int*)(unsigned int)(uintptr_t)l;
  __builtin_amdgcn_global_load_lds(gp, lp, 16, 0, 0);
}

// ---------------------------------------------------------------------------
// prep_k: casts + weight transposes + out-proj fold.
// ---------------------------------------------------------------------------
__global__ __launch_bounds__(256) void prep_k(
    const float* __restrict__ x0, const float* __restrict__ x1,
    const float* __restrict__ Wqk, const float* __restrict__ Wv,
    const float* __restrict__ W0, const float* __restrict__ W3,
    const float* __restrict__ Wout,
    const float* __restrict__ bqk, const float* __restrict__ bv,
    const float* __restrict__ b0, const float* __restrict__ bout,
    us* __restrict__ x0b, us* __restrict__ x1b,
    us* __restrict__ Wqvt, us* __restrict__ W1t, us* __restrict__ W3t,
    float* __restrict__ bias_qv, float* __restrict__ bias1) {
  const int bid = blockIdx.x, t = threadIdx.x;
  if (bid < 4096) {
    const int n4 = (MROWS * DMODEL) / 4;
    int i = bid * 256 + t;
    const float* src = (i < n4) ? x0 : x1;
    us* dst = (i < n4) ? x0b : x1b;
    int j = (i < n4) ? i : i - n4;
    float4 v = *(const float4*)&src[j * 4];
    ushort4 o = {f2bf(v.x), f2bf(v.y), f2bf(v.z), f2bf(v.w)};
    *(ushort4*)&dst[j * 4] = o;
  } else if (bid < 5634) {
    int gid = (bid - 4096) * 256 + t;
    if (gid < 65536) {
      int k = gid >> 8, j = gid & 255;
      Wqvt[j * 256 + k] = f2bf(Wqk[gid]);
    } else if (gid < 131072) {
      int i = gid - 65536;
      int k = i >> 8, j = i & 255;
      Wqvt[(256 + j) * 256 + k] = f2bf(Wv[i]);
    } else if (gid < 262144) {
      int i = gid - 131072;
      int k = i >> 9, j = i & 511;
      W1t[j * 512 + k] = f2bf(W0[i]);
    } else if (gid < 393216) {
      int i = gid - 262144;
      int k = i >> 8, j = i & 255;
      W3t[j * 512 + k] = f2bf(W3[i]);
    } else if (gid < 393728) {
      int j = gid - 393216;
      bias_qv[j] = (j < 256) ? bqk[j] : bv[j - 256];
    }
  } else {
    int i = bid - 5634;  // [0,257)
    if (i < 256) {
      float a0 = 0.f, a1 = 0.f;
      for (int k0 = 0; k0 < 256; k0 += 8) {
        float wk[8], r0[8], r1[8];
#pragma unroll
        for (int u = 0; u < 8; ++u) {
          wk[u] = Wout[i * 256 + k0 + u];
          const float* row = &W0[(size_t)(256 + k0 + u) * 512];
          r0[u] = row[t];
          r1[u] = row[t + 256];
        }
#pragma unroll
        for (int u = 0; u < 8; ++u) { a0 += wk[u] * r0[u]; a1 += wk[u] * r1[u]; }
      }
      W1t[t * 512 + 256 + i] = f2bf(a0);
      W1t[(t + 256) * 512 + 256 + i] = f2bf(a1);
    } else {
      float a0 = b0[t], a1 = b0[t + 256];
      for (int k = 0; k < 256; ++k) {
        float bk = bout[k];
        const float* row = &W0[(size_t)(256 + k) * 512];
        a0 += bk * row[t];
        a1 += bk * row[t + 256];
      }
      bias1[t] = a0;
      bias1[t + 256] = a1;
    }
  }
}

// ---------------------------------------------------------------------------
// gemm8: round-4 gemm2 structure (REGISTER staging — the measured-fast one).
// Tile M=128 x N=64, BK=64; 4 waves, wave w = rows [w*32, w*32+32).
// Loads issued before the barrier -> compiler pipelines across prior MFMA.
//   MODE 0 (QV, N=512 grid.y=8): coltile<4 -> qk bf16 *QKSCALE natural;
//                                coltile>=4 -> Vt per-head transposed
//   MODE 1 (FFN1, N=512): A = concat(Ax, Am) along K (lda=256 each); bf16 out
//   MODE 2 (FFN2, N=256): fp32 out = resid + A@W + bias
// ---------------------------------------------------------------------------
template <int MODE>
__global__ __launch_bounds__(256) void gemm8(
    const us* __restrict__ A_0, const us* __restrict__ A_1,
    const us* __restrict__ A2_0, const us* __restrict__ A2_1,
    const us* __restrict__ Wt, const float* __restrict__ bias,
    const float* __restrict__ r0_, const float* __restrict__ r1_,
    void* __restrict__ C0_, void* __restrict__ C1_,
    void* __restrict__ V0_, void* __restrict__ V1_, int K) {
  __shared__ us lds[12288];  // 24 KB: A [0,8192), B [8192,12288)

  const int t = threadIdx.x;
  const int w = t >> 6, lane = t & 63;
  const int qd = lane >> 4, l15 = lane & 15;
  const int row0 = blockIdx.x * 128;
  const int coltile = blockIdx.y, col0 = coltile * 64;
  const int z = blockIdx.z;
  const us* A = z ? A_1 : A_0;
  const us* A2 = z ? A2_1 : A2_0;

  f32x4 acc[2][4];
#pragma unroll
  for (int mh = 0; mh < 2; ++mh)
#pragma unroll
    for (int tn = 0; tn < 4; ++tn) acc[mh][tn] = (f32x4){0.f, 0.f, 0.f, 0.f};

  for (int k0 = 0; k0 < K; k0 += 64) {
    __syncthreads();
    // 24 staging tasks: 16 A granules + 8 B granules; load->ds_write.
#pragma unroll
    for (int pp = 0; pp < 6; ++pp) {
      int g = pp * 4 + w;
      uint4 d;
      if (g < 16) {
        int tm = g >> 1, s = g & 1;
        const us* Ap = A;
        int kk = k0 + s * 32 + qd * 8, lda = K;
        if (MODE == 1) {
          Ap = (k0 < 256) ? A : A2;
          kk = (k0 & 255) + s * 32 + qd * 8;
          lda = 256;
        }
        d = *(const uint4*)&Ap[(size_t)(row0 + tm * 16 + l15) * lda + kk];
        *(uint4*)&lds[(g * 64 + lane) * 8] = d;
      } else {
        int tn = (g - 16) >> 1, s = g & 1;
        d = *(const uint4*)&Wt[(size_t)(col0 + tn * 16 + l15) * K + k0 + s * 32 + qd * 8];
        *(uint4*)&lds[8192 + (((tn * 2 + s) * 64 + lane)) * 8] = d;
      }
    }
    __syncthreads();

    bf16x8 aA[2][2];
#pragma unroll
    for (int mh = 0; mh < 2; ++mh)
#pragma unroll
      for (int s = 0; s < 2; ++s)
        aA[mh][s] = *(const bf16x8*)&lds[((((w * 2 + mh) * 2 + s)) * 64 + lane) * 8];
#pragma unroll
    for (int tn = 0; tn < 4; ++tn) {
      bf16x8 b0v = *(const bf16x8*)&lds[8192 + ((tn * 2 + 0) * 64 + lane) * 8];
      bf16x8 b1v = *(const bf16x8*)&lds[8192 + ((tn * 2 + 1) * 64 + lane) * 8];
#pragma unroll
      for (int mh = 0; mh < 2; ++mh) {
        acc[mh][tn] = __builtin_amdgcn_mfma_f32_16x16x32_bf16(aA[mh][0], b0v, acc[mh][tn], 0, 0, 0);
        acc[mh][tn] = __builtin_amdgcn_mfma_f32_16x16x32_bf16(aA[mh][1], b1v, acc[mh][tn], 0, 0, 0);
      }
    }
  }

  // C-layout: row = row0 + w*32 + mh*16 + qd*4 + r, col = col0 + tn*16 + l15.
  if (MODE == 0 && coltile >= 4) {
    // Vt per-head transposed via LDS bounce (stride 130: conflict-free).
    __syncthreads();
    int h_ = coltile - 4;
#pragma unroll
    for (int tn = 0; tn < 4; ++tn) {
      int col = col0 + tn * 16 + l15;  // [256,512)
      float bb = bias[col];
#pragma unroll
      for (int mh = 0; mh < 2; ++mh)
#pragma unroll
        for (int r = 0; r < 4; ++r) {
          int rloc = w * 32 + mh * 16 + qd * 4 + r;
          lds[(tn * 16 + l15) * 130 + rloc] = f2bf(acc[mh][tn][r] + bb);
        }
    }
    __syncthreads();
    us* Vt = (us*)(z ? V1_ : V0_);
    int b_ = row0 >> 11;
    int seq0 = row0 & 2047;
    for (int c = t; c < 1024; c += 256) {
      int dloc = c >> 4, scc = c & 15;
      uint4 d = *(const uint4*)&lds[dloc * 130 + scc * 8];
      *(uint4*)&Vt[((size_t)(b_ * NH + h_) * HD + dloc) * SEQ + seq0 + scc * 8] = d;
    }
    return;
  }

#pragma unroll
  for (int tn = 0; tn < 4; ++tn) {
    int col = col0 + tn * 16 + l15;
    float bb = bias[col];
#pragma unroll
    for (int mh = 0; mh < 2; ++mh)
#pragma unroll
      for (int r = 0; r < 4; ++r) {
        size_t grow = row0 + w * 32 + mh * 16 + qd * 4 + r;
        float v = acc[mh][tn][r] + bb;
        if (MODE == 0) {
          ((us*)(z ? C1_ : C0_))[grow * 256 + col] = f2bf(v * QKSCALE);
        } else if (MODE == 1) {
          ((us*)(z ? C1_ : C0_))[grow * 512 + col] = f2bf(v);
        } else {
          const float* R = z ? r1_ : r0_;
          ((float*)(z ? C1_ : C0_))[grow * 256 + col] = R[grow * 256 + col] + v;
        }
      }
  }
}

// ---------------------------------------------------------------------------
// flash_v7 (proven 51 us): register-P MFMA flash, kv-split x2, both dirs,
// dbuf DMA prefetch, v_perm P-packing, XCD remap.
// ---------------------------------------------------------------------------
__global__ __launch_bounds__(256) void flash_v7(
    const us* __restrict__ qk0, const us* __restrict__ qk1,
    const us* __restrict__ vt0, const us* __restrict__ vt1,
    float* __restrict__ Opart, float* __restrict__ lpart) {
  __shared__ us lds[16384];  // 2 x 16KB buffers
  const int t = threadIdx.x, w = t >> 6, lane = t & 63;
  const int qd = lane >> 4, l15 = lane & 15;

  const int flat = blockIdx.x + 32 * (blockIdx.y + 4 * blockIdx.z);
  const int xcd = flat & 7, slot = flat >> 3;
  const int combo = (xcd << 2) + (slot >> 5);
  const int qs = slot & 31;
  const int qt = qs & 15, half = qs >> 4;
  const int dir = combo >> 4, bh = combo & 15, b = bh >> 2, h = bh & 3;

  const us* Qb = dir ? qk1 : qk0;
  const us* Kb = dir ? qk0 : qk1;
  const us* Vt = dir ? vt0 : vt1;
  float* Op = Opart + (size_t)(dir * 2 + half) * (MROWS * DMODEL);
  float* lp = lpart + ((size_t)(dir * 2 + half) * NH + h) * MROWS;
  const size_t qrow0 = (size_t)b * SEQ + (size_t)qt * 128;
  const int hoff = h * HD;
  const us* vtb = Vt + (size_t)(b * NH + h) * HD * SEQ;
  const int kt0 = half * 16;

  const us* sp[4];
  int sstr[4];
#pragma unroll
  for (int pp = 0; pp < 4; ++pp) {
    int g = pp * 4 + w;
    if (g < 8) {
      int tk = g >> 1, s = g & 1;
      int kvl = (tk >> 1) * 32 + (l15 >> 2) * 8 + (tk & 1) * 4 + (l15 & 3);  // pi
      sp[pp] = &Kb[(size_t)(b * SEQ + kt0 * 64 + kvl) * DMODEL + hoff + s * 32 + qd * 8];
      sstr[pp] = 64 * DMODEL;
    } else {
      int td = (g - 8) >> 1, s = g & 1;
      sp[pp] = &vtb[(size_t)(td * 16 + l15) * SEQ + kt0 * 64 + s * 32 + qd * 8];
      sstr[pp] = 64;
    }
  }

  bf16x8 qf[2][2];
#pragma unroll
  for (int qh = 0; qh < 2; ++qh)
#pragma unroll
    for (int s = 0; s < 2; ++s)
      qf[qh][s] = *(const bf16x8*)&Qb[(qrow0 + w * 32 + qh * 16 + l15) * DMODEL + hoff + s * 32 + qd * 8];

  f32x4 Oacc[2][4];
#pragma unroll
  for (int qh = 0; qh < 2; ++qh)
#pragma unroll
    for (int td = 0; td < 4; ++td) Oacc[qh][td] = (f32x4){0.f, 0.f, 0.f, 0.f};
  float l_lane[2] = {0.f, 0.f};

#pragma unroll
  for (int pp = 0; pp < 4; ++pp) {
    dma16(sp[pp], &lds[(pp * 4 + w) * 512]);
    sp[pp] += sstr[pp];
  }
  __syncthreads();

  int bsel = 0;
  for (int it = 0; it < 16; ++it) {
    if (it < 15) {
#pragma unroll
      for (int pp = 0; pp < 4; ++pp) {
        dma16(sp[pp], &lds[(bsel ^ 1) * 8192 + (pp * 4 + w) * 512]);
        sp[pp] += sstr[pp];
      }
    }
    const us* L = &lds[bsel * 8192];

    bf16x8 kf[4][2], vf[4][2];
#pragma unroll
    for (int tk = 0; tk < 4; ++tk)
#pragma unroll
      for (int s = 0; s < 2; ++s) {
        kf[tk][s] = *(const bf16x8*)&L[((tk * 2 + s) * 64 + lane) * 8];
        vf[tk][s] = *(const bf16x8*)&L[((8 + tk * 2 + s) * 64 + lane) * 8];
      }

#pragma unroll
    for (int qh = 0; qh < 2; ++qh) {
      f32x4 S[4];
#pragma unroll
      for (int tk = 0; tk < 4; ++tk) {
        f32x4 a = {0.f, 0.f, 0.f, 0.f};
        a = __builtin_amdgcn_mfma_f32_16x16x32_bf16(kf[tk][0], qf[qh][0], a, 0, 0, 0);
        a = __builtin_amdgcn_mfma_f32_16x16x32_bf16(kf[tk][1], qf[qh][1], a, 0, 0, 0);
        S[tk] = a;
      }
      float p[4][4];
      float rs = 0.f;
#pragma unroll
      for (int tk = 0; tk < 4; ++tk)
#pragma unroll
        for (int r = 0; r < 4; ++r) {
          float pv = EXP2(S[tk][r]);
          p[tk][r] = pv;
          rs += pv;
        }
      l_lane[qh] += rs;
      union { bf16x8 v; unsigned int u[4]; } pk0, pk1;
      pk0.u[0] = pk2bf(p[0][0], p[0][1]);
      pk0.u[1] = pk2bf(p[0][2], p[0][3]);
      pk0.u[2] = pk2bf(p[1][0], p[1][1]);
      pk0.u[3] = pk2bf(p[1][2], p[1][3]);
      pk1.u[0] = pk2bf(p[2][0], p[2][1]);
      pk1.u[1] = pk2bf(p[2][2], p[2][3]);
      pk1.u[2] = pk2bf(p[3][0], p[3][1]);
      pk1.u[3] = pk2bf(p[3][2], p[3][3]);
#pragma unroll
      for (int td = 0; td < 4; ++td) {
        Oacc[qh][td] = __builtin_amdgcn_mfma_f32_16x16x32_bf16(pk0.v, vf[td][0], Oacc[qh][td], 0, 0, 0);
        Oacc[qh][td] = __builtin_amdgcn_mfma_f32_16x16x32_bf16(pk1.v, vf[td][1], Oacc[qh][td], 0, 0, 0);
      }
    }
    __syncthreads();
    bsel ^= 1;
  }

#pragma unroll
  for (int qh = 0; qh < 2; ++qh) {
    float l = l_lane[qh];
    l += __shfl_xor(l, 16);
    l += __shfl_xor(l, 32);
    if (qd == 0) lp[qrow0 + w * 32 + qh * 16 + l15] = l;
#pragma unroll
    for (int r = 0; r < 4; ++r) {
      size_t row = qrow0 + w * 32 + qh * 16 + qd * 4 + r;
#pragma unroll
      for (int td = 0; td < 4; ++td)
        Op[row * DMODEL + hoff + td * 16 + l15] = Oacc[qh][td][r];
    }
  }
}

// ---------------------------------------------------------------------------
// Merge kv-halves: m = (Oa + Ob) / (la + lb), bf16 out.
// ---------------------------------------------------------------------------
__global__ __launch_bounds__(256) void combine_k(
    const float* __restrict__ Opart, const float* __restrict__ lpart,
    us* __restrict__ m0b, us* __restrict__ m1b) {
  int gid = blockIdx.x * 256 + threadIdx.x;
  int dir = gid >= (MROWS * DMODEL / 4);
  int idx = gid - dir * (MROWS * DMODEL / 4);
  int row = idx >> 6;
  int c4 = (idx & 63) << 2;
  int h = c4 >> 6;
  const float* Oa = Opart + (size_t)(dir * 2 + 0) * (MROWS * DMODEL);
  const float* Ob = Opart + (size_t)(dir * 2 + 1) * (MROWS * DMODEL);
  float la = lpart[((size_t)(dir * 2 + 0) * NH + h) * MROWS + row];
  float lb = lpart[((size_t)(dir * 2 + 1) * NH + h) * MROWS + row];
  float inv = 1.0f / (la + lb);
  float4 a = *(const float4*)&Oa[(size_t)row * DMODEL + c4];
  float4 bv = *(const float4*)&Ob[(size_t)row * DMODEL + c4];
  us* m = dir ? m1b : m0b;
  ushort4 o = {f2bf((a.x + bv.x) * inv), f2bf((a.y + bv.y) * inv),
               f2bf((a.z + bv.z) * inv), f2bf((a.w + bv.w) * inv)};
  *(ushort4*)&m[(size_t)row * DMODEL + c4] = o;
}

// ---------------------------------------------------------------------------
// LayerNorm(512) + exact GELU: one wave per row (proven ~5 us).
// ---------------------------------------------------------------------------
__global__ __launch_bounds__(256) void ln_gelu3(
    us* __restrict__ Y0, us* __restrict__ Y1,
    const float* __restrict__ sc, const float* __restrict__ bi) {
  int w = threadIdx.x >> 6, lane = threadIdx.x & 63;
  int ridx = blockIdx.x * 4 + w;
  us* Y = (ridx >= MROWS) ? Y1 : Y0;
  int row = ridx & (MROWS - 1);
  us* p = Y + (size_t)row * 512 + lane * 8;
  uint4 u = *(const uint4*)p;
  unsigned int uu[4] = {u.x, u.y, u.z, u.w};
  float v[8];
#pragma unroll
  for (int i = 0; i < 4; ++i) {
    v[2 * i] = bf2f((us)(uu[i] & 0xFFFF));
    v[2 * i + 1] = bf2f((us)(uu[i] >> 16));
  }
  float s1 = 0.f, s2 = 0.f;
#pragma unroll
  for (int i = 0; i < 8; ++i) { s1 += v[i]; s2 += v[i] * v[i]; }
#pragma unroll
  for (int m = 1; m < 64; m <<= 1) {
    s1 += __shfl_xor(s1, m);
    s2 += __shfl_xor(s2, m);
  }
  float mu = s1 * (1.0f / 512.0f);
  float var = s2 * (1.0f / 512.0f) - mu * mu;
  float rstd = rsqrtf(var + 1e-5f);
  int c0 = lane * 8;
  float4 scA = *(const float4*)&sc[c0], scB = *(const float4*)&sc[c0 + 4];
  float4 biA = *(const float4*)&bi[c0], biB = *(const float4*)&bi[c0 + 4];
  float scv[8] = {scA.x, scA.y, scA.z, scA.w, scB.x, scB.y, scB.z, scB.w};
  float biv[8] = {biA.x, biA.y, biA.z, biA.w, biB.x, biB.y, biB.z, biB.w};
  unsigned int ou[4];
#pragma unroll
  for (int i = 0; i < 4; ++i) {
    float y0 = (v[2 * i] - mu) * rstd * scv[2 * i] + biv[2 * i];
    float y1 = (v[2 * i + 1] - mu) * rstd * scv[2 * i + 1] + biv[2 * i + 1];
    y0 = 0.5f * y0 * (1.0f + erff(y0 * 0.70710678118654752f));
    y1 = 0.5f * y1 * (1.0f + erff(y1 * 0.70710678118654752f));
    ou[i] = (unsigned int)f2bf(y0) | ((unsigned int)f2bf(y1) << 16);
  }
  uint4 o = {ou[0], ou[1], ou[2], ou[3]};
  *(uint4*)p = o;
}

// ---------------------------------------------------------------------------
// Workspace (byte offsets), total 67 MB:
//   0/4: x0b,x1b | 8: Wqvt,W1t,W3t | 9: biases | 10/14: qk | 18/22: vt
//   26/30: m0b,m1b | y0b/y1b overlay 10/18 | 34-66: Opart[4] | 66: lpart
// ---------------------------------------------------------------------------
extern "C" void kernel_launch(void* const* d_in, const int* in_sizes, int n_in,
                              void* d_out, int out_size, void* d_ws,
                              size_t ws_size, hipStream_t stream) {
  const float* x0   = (const float*)d_in[0];
  const float* x1   = (const float*)d_in[1];
  const float* Wqk  = (const float*)d_in[2];
  const float* bqk  = (const float*)d_in[3];
  const float* Wv   = (const float*)d_in[4];
  const float* bv   = (const float*)d_in[5];
  const float* Wout = (const float*)d_in[6];
  const float* bout = (const float*)d_in[7];
  const float* W0   = (const float*)d_in[8];
  const float* b0   = (const float*)d_in[9];
  const float* lns  = (const float*)d_in[10];
  const float* lnb  = (const float*)d_in[11];
  const float* W3   = (const float*)d_in[12];
  const float* b3   = (const float*)d_in[13];

  char* ws = (char*)d_ws;
  const size_t MB = 1024 * 1024;
  us* x0b  = (us*)(ws + 0 * MB);
  us* x1b  = (us*)(ws + 4 * MB);
  us* Wqvt = (us*)(ws + 8 * MB);
  us* W1t  = (us*)(ws + 8 * MB + 262144);
  us* W3t  = (us*)(ws + 8 * MB + 786432);
  float* bias_qv = (float*)(ws + 9 * MB);
  float* bias1   = (float*)(ws + 9 * MB + 4096);
  us* qk0b = (us*)(ws + 10 * MB);
  us* qk1b = (us*)(ws + 14 * MB);
  us* vt0  = (us*)(ws + 18 * MB);
  us* vt1  = (us*)(ws + 22 * MB);
  us* m0b  = (us*)(ws + 26 * MB);
  us* m1b  = (us*)(ws + 30 * MB);
  us* y0b  = (us*)(ws + 10 * MB);  // overlay qk (dead after flash)
  us* y1b  = (us*)(ws + 18 * MB);  // overlay vt (dead after flash)
  float* Opart = (float*)(ws + 34 * MB);
  float* lpart = (float*)(ws + 66 * MB);
  float* out0 = (float*)d_out;
  float* out1 = out0 + (size_t)MROWS * DMODEL;

  dim3 blk(256);

  prep_k<<<dim3(5891), blk, 0, stream>>>(x0, x1, Wqk, Wv, W0, W3, Wout,
                                         bqk, bv, b0, bout,
                                         x0b, x1b, Wqvt, W1t, W3t,
                                         bias_qv, bias1);

  // QK+V projection fused (N=512): coltile 0-3 qk scaled, 4-7 vt transposed
  gemm8<0><<<dim3(64, 8, 2), blk, 0, stream>>>(
      x0b, x1b, nullptr, nullptr, Wqvt, bias_qv, nullptr, nullptr,
      qk0b, qk1b, vt0, vt1, 256);

  // Bidirectional cross attention (kv-split x2), then merge
  flash_v7<<<dim3(32, 4, 8), blk, 0, stream>>>(qk0b, qk1b, vt0, vt1, Opart, lpart);
  combine_k<<<dim3(4096), blk, 0, stream>>>(Opart, lpart, m0b, m1b);

  // FFN1 (out-proj folded): y = concat(x, m) @ [W0top; Wcomb] + bias1
  gemm8<1><<<dim3(64, 8, 2), blk, 0, stream>>>(
      x0b, x1b, m0b, m1b, W1t, bias1, nullptr, nullptr,
      y0b, y1b, nullptr, nullptr, 512);

  // LayerNorm + GELU (both streams)
  ln_gelu3<<<dim3(4096), blk, 0, stream>>>(y0b, y1b, lns, lnb);

  // FFN2: out = x + y @ W3 + b3 (fp32)
  gemm8<2><<<dim3(64, 4, 2), blk, 0, stream>>>(
      y0b, y1b, nullptr, nullptr, W3t, b3, x0, x1,
      out0, out1, nullptr, nullptr, 512);
}